// Round 1
// baseline (264.029 us; speedup 1.0000x reference)
//
#include <hip/hip_runtime.h>

#define T_DIM 2048
#define B_DIM 16
#define C_DIM 512
#define H_DIM 8
#define K_DIM 7
#define NW 56            // H*K
#define ROWS (T_DIM * B_DIM)

// ---------------------------------------------------------------------------
// Kernel 1: wsw[row][n] = softmax_over_7( query[row,:] @ W[:, n] )
// Block = 256 threads = 4 waves; block owns 64 rows (lane = row).
// Wave wq handles n-quarter [wq*14, wq*14+14) = 2 heads -> softmax lane-local.
// W accessed via wave-uniform addresses -> scalar (s_load) path.
// q staged via LDS transpose: 16 planes of 4 c-values, plane stride 260 dwords
// (260 mod 32 = 4 -> ~2-way conflicts; float4-aligned since 260 = 4*65).
// ---------------------------------------------------------------------------
__global__ __launch_bounds__(256, 2)
void weights_kernel(const float* __restrict__ q, const float* __restrict__ W,
                    float* __restrict__ wsw) {
    __shared__ __align__(16) float qt[16 * 260];

    const int t    = threadIdx.x;
    const int lane = t & 63;
    const int wq   = __builtin_amdgcn_readfirstlane(t >> 6);  // 0..3, SGPR
    const int r0   = blockIdx.x * 64;

    float acc[14];
#pragma unroll
    for (int n = 0; n < 14; ++n) acc[n] = 0.f;

    const int c4    = t & 15;   // staging plane
    const int rbase = t >> 4;   // 0..15

    for (int cb = 0; cb < 8; ++cb) {   // 8 chunks of 64 c
        __syncthreads();
#pragma unroll
        for (int j = 0; j < 4; ++j) {
            const int row = rbase + j * 16;
            const float4 v = *(const float4*)(q + (size_t)(r0 + row) * C_DIM
                                                + cb * 64 + c4 * 4);
            *(float4*)(&qt[c4 * 260 + row * 4]) = v;
        }
        __syncthreads();
#pragma unroll 2
        for (int p = 0; p < 16; ++p) {
            const float4 qv = *(const float4*)(&qt[p * 260 + lane * 4]);
            const float qs[4] = {qv.x, qv.y, qv.z, qv.w};
#pragma unroll
            for (int i = 0; i < 4; ++i) {
                const int c = cb * 64 + p * 4 + i;
                const float* wp = W + c * NW + wq * 14;   // uniform -> s_load
#pragma unroll
                for (int n = 0; n < 14; ++n)
                    acc[n] = fmaf(qs[i], wp[n], acc[n]);
            }
        }
    }

    // softmax over each group of 7 (2 heads per lane), then store
    const size_t row = (size_t)(r0 + lane);
    float* op = wsw + row * NW + wq * 14;
#pragma unroll
    for (int hh = 0; hh < 2; ++hh) {
        float m = acc[hh * 7];
#pragma unroll
        for (int k = 1; k < 7; ++k) m = fmaxf(m, acc[hh * 7 + k]);
        float e[7];
        float s = 0.f;
#pragma unroll
        for (int k = 0; k < 7; ++k) {
            e[k] = __expf(acc[hh * 7 + k] - m);
            s += e[k];
        }
        const float inv = __builtin_amdgcn_rcpf(s);
#pragma unroll
        for (int k = 0; k < 7; ++k) op[hh * 7 + k] = e[k] * inv;
    }
}

// ---------------------------------------------------------------------------
// Kernel 2: out[t,b,h*64+r] = sum_kk w[t,b,h,kk] * x_pad[t + f/512, b, f%512],
//           f = h*448 + r*7 + kk.
// Block = 16 t-values x 1 b. x_pad rows t0-3..t0+18 staged contiguously in LDS
// (stride 512) => LDS address = tt*512 + f0 + kk, CONTIGUOUS in kk.
// lane = r (so h is wave-uniform -> weights via s_load).
// LDS 45056 B -> 3 blocks/CU. x reads: lane stride 7 dwords, conflict-free.
// ---------------------------------------------------------------------------
__global__ __launch_bounds__(256)
void conv_kernel(const float* __restrict__ x, const float* __restrict__ wsw,
                 float* __restrict__ out) {
    __shared__ __align__(16) float xs[22 * 512];

    const int t  = threadIdx.x;
    const int b  = blockIdx.x & 15;
    const int t0 = (blockIdx.x >> 4) * 16;

    // stage 22 rows of x_pad for this b (zeros outside [0,T))
#pragma unroll
    for (int j = 0; j < 11; ++j) {
        const int idx = t + j * 256;     // float4 index, 0..2815
        const int i   = idx >> 7;        // padded row 0..21
        const int c   = (idx & 127) * 4;
        const int tp  = t0 + i - 3;
        float4 v = make_float4(0.f, 0.f, 0.f, 0.f);
        if (tp >= 0 && tp < T_DIM)
            v = *(const float4*)(x + (size_t)(tp * B_DIM + b) * C_DIM + c);
        *(float4*)(&xs[i * 512 + c]) = v;
    }
    __syncthreads();

    const int lane = t & 63;
    const int wid  = __builtin_amdgcn_readfirstlane(t >> 6);  // 0..3, SGPR

    for (int tt = 0; tt < 16; ++tt) {
        const int trow = t0 + tt;
        const float* wrow = wsw + (size_t)(trow * B_DIM + b) * NW;
        float* orow       = out + (size_t)(trow * B_DIM + b) * C_DIM;
#pragma unroll
        for (int g = 0; g < 2; ++g) {
            const int h = wid + g * 4;                 // wave-uniform (SGPR)
            const float* wp = wrow + h * 7;            // uniform -> s_load
            const int f0 = h * 448 + lane * 7;
            const float* xp = &xs[tt * 512 + f0];
            float a = 0.f;
#pragma unroll
            for (int kk = 0; kk < 7; ++kk)
                a = fmaf(wp[kk], xp[kk], a);
            orow[h * 64 + lane] = a;
        }
    }
}

extern "C" void kernel_launch(void* const* d_in, const int* in_sizes, int n_in,
                              void* d_out, int out_size, void* d_ws, size_t ws_size,
                              hipStream_t stream) {
    const float* x = (const float*)d_in[0];
    const float* q = (const float*)d_in[1];
    const float* W = (const float*)d_in[2];
    float* out = (float*)d_out;
    float* wsw = (float*)d_ws;   // ROWS*NW floats = 7,340,032 bytes

    weights_kernel<<<ROWS / 64, 256, 0, stream>>>(q, W, wsw);
    conv_kernel<<<(T_DIM / 16) * B_DIM, 256, 0, stream>>>(x, wsw, out);
}

// Round 2
// 201.953 us; speedup vs baseline: 1.3074x; 1.3074x over previous
//
#include <hip/hip_runtime.h>

#define T_DIM 2048
#define B_DIM 16
#define C_DIM 512
#define NW 56            // H*K
#define ROWS (T_DIM * B_DIM)
#define SA 136           // LDS k-stride (bf16 elems) for A and Bt tiles (272B = 17*16)

typedef __attribute__((ext_vector_type(8))) short short8;
typedef __attribute__((ext_vector_type(4))) short short4v;
typedef __attribute__((ext_vector_type(4))) float floatx4;

static __device__ __forceinline__ unsigned short f2bf(float x) {
    union { float f; unsigned u; } v; v.f = x;
    return (unsigned short)((v.u + 0x7FFFu + ((v.u >> 16) & 1u)) >> 16);  // RNE
}

// ---------------------------------------------------------------------------
// Kernel 1: logits = q(32768x512) @ W(512x56->64), bf16 MFMA, fused softmax.
// Block: 64 rows x 64 n, 256 threads = 4 waves; wave wv owns rows wv*16..+16,
// all 4 n-tiles. K staged in 4 chunks of 128 (fp32->bf16 convert in staging).
// A LDS [row][k] k-contig; B staged TRANSPOSED [n][k] k-contig so both frags
// load as one ds_read_b128 (lane: row=l&15, k=(l>>4)*8+j — m89/m120 layout).
// Epilogue: D frags -> LDS tile (stride 65) -> per-(row,head) softmax -> wsw.
// ---------------------------------------------------------------------------
__global__ __launch_bounds__(256)
void weights_kernel(const float* __restrict__ q, const float* __restrict__ W,
                    float* __restrict__ wsw) {
    __shared__ union {
        struct { unsigned short A[64 * SA]; unsigned short Bt[64 * SA]; } s;
        float L[64 * 65];
    } u;

    const int tid  = threadIdx.x;
    const int lane = tid & 63;
    const int wv   = tid >> 6;
    const int r0   = blockIdx.x * 64;

    floatx4 acc[4];
#pragma unroll
    for (int nt = 0; nt < 4; ++nt) acc[nt] = (floatx4){0.f, 0.f, 0.f, 0.f};

    const int arow = tid >> 2;          // 0..63
    const int acol = (tid & 3) * 4;     // float4 col within +i*16
    const int bk   = tid >> 1;          // 0..127
    const int bn0  = (tid & 1) * 28;    // 0 or 28
    const int m    = lane & 15, quad = lane >> 4;

    for (int kc = 0; kc < 512; kc += 128) {
        __syncthreads();
        // ---- stage A: 64 rows x 128 k, fp32 global -> bf16 LDS ----
        const float* qp = q + (size_t)(r0 + arow) * C_DIM + kc + acol;
#pragma unroll
        for (int i = 0; i < 8; ++i) {
            const float4 v = *(const float4*)(qp + i * 16);
            short4v p;
            p.x = (short)f2bf(v.x); p.y = (short)f2bf(v.y);
            p.z = (short)f2bf(v.z); p.w = (short)f2bf(v.w);
            *(short4v*)(&u.s.A[arow * SA + acol + i * 16]) = p;
        }
        // ---- stage Bt: 64 n x 128 k transposed, zero-pad n in [56,64) ----
        const float* wp = W + (size_t)(kc + bk) * NW + bn0;
#pragma unroll
        for (int j = 0; j < 28; ++j)
            u.s.Bt[(bn0 + j) * SA + bk] = f2bf(wp[j]);
        {
            const int n  = 56 + (tid & 7);
            const int k0 = (tid >> 3) * 4;
#pragma unroll
            for (int j = 0; j < 4; ++j) u.s.Bt[n * SA + k0 + j] = 0;
        }
        __syncthreads();
        // ---- MFMA: 4 ktiles x 4 ntiles ----
#pragma unroll
        for (int kt = 0; kt < 4; ++kt) {
            const short8 af = *(const short8*)(&u.s.A[(wv * 16 + m) * SA + kt * 32 + quad * 8]);
#pragma unroll
            for (int nt = 0; nt < 4; ++nt) {
                const short8 bf = *(const short8*)(&u.s.Bt[(nt * 16 + m) * SA + kt * 32 + quad * 8]);
                acc[nt] = __builtin_amdgcn_mfma_f32_16x16x32_bf16(af, bf, acc[nt], 0, 0, 0);
            }
        }
    }
    __syncthreads();   // all mfma LDS reads done; reuse LDS as logit tile
#pragma unroll
    for (int nt = 0; nt < 4; ++nt)
#pragma unroll
        for (int r = 0; r < 4; ++r)
            u.L[(wv * 16 + quad * 4 + r) * 65 + nt * 16 + m] = acc[nt][r];
    __syncthreads();
    // ---- softmax over groups of 7: 64 rows x 8 heads = 512 tasks ----
#pragma unroll
    for (int rep = 0; rep < 2; ++rep) {
        const int id  = tid + rep * 256;
        const int row = id >> 3, h = id & 7;
        const float* Lp = &u.L[row * 65 + h * 7];
        float mx = Lp[0];
#pragma unroll
        for (int k = 1; k < 7; ++k) mx = fmaxf(mx, Lp[k]);
        float e[7], s = 0.f;
#pragma unroll
        for (int k = 0; k < 7; ++k) { e[k] = __expf(Lp[k] - mx); s += e[k]; }
        const float inv = 1.0f / s;
        float* op = wsw + (size_t)(r0 + row) * NW + h * 7;
#pragma unroll
        for (int k = 0; k < 7; ++k) op[k] = e[k] * inv;
    }
}

// ---------------------------------------------------------------------------
// Kernel 2: out[t,b,h*64+r] = sum_k w[t,b,h,k] * xwin[t][f], f=h*448+r*7+k.
// Block = 16 t x 1 b. x_pad rows staged at stride 512 (f-linear addressing).
// Lane l owns outputs c = 8l..8l+8  <=>  window floats [56l, 56l+56): exactly
// 14 aligned float4 -> ds_read_b128. Raw banks collide 16-way (56 = 24 mod 32,
// 448 = 0 mod 32), so both staging writes and reads apply the XOR swizzle
// addr ^= (addr>>2)&0x70 (permutes 16B blocks within 128B, ~2-way residual).
// Weights via coalesced LDS tile (16x56); broadcast reads are conflict-free
// (7h mod 32 distinct for h<8). No s_loads anywhere in the hot loop.
// ---------------------------------------------------------------------------
static __device__ __forceinline__ int swz(int ba) { return ba ^ ((ba >> 2) & 0x70); }

__global__ __launch_bounds__(256)
void conv_kernel(const float* __restrict__ x, const float* __restrict__ wsw,
                 float* __restrict__ out) {
    __shared__ float xs[22 * 512];    // 45056 B
    __shared__ float wt[16 * NW];     // 3584 B -> 3 blocks/CU

    const int tid = threadIdx.x;
    const int b   = blockIdx.x & 15;
    const int t0  = (blockIdx.x >> 4) * 16;

    // stage 22 x_pad rows (zeros outside [0,T)), swizzled
#pragma unroll
    for (int j = 0; j < 11; ++j) {
        const int idx = tid + j * 256;       // float4 index 0..2815
        const int i   = idx >> 7;            // padded row 0..21
        const int c   = (idx & 127) * 4;
        const int tp  = t0 + i - 3;
        float4 v = make_float4(0.f, 0.f, 0.f, 0.f);
        if (tp >= 0 && tp < T_DIM)
            v = *(const float4*)(x + (size_t)(tp * B_DIM + b) * C_DIM + c);
        *(float4*)((char*)xs + swz(idx * 16)) = v;
    }
    // stage softmaxed weights tile: 16 rows x 56, coalesced
    if (tid < 224) {
        const int tt = tid / 14, sg = tid % 14;
        const float* src = wsw + ((size_t)(t0 + tt) * B_DIM + b) * NW + sg * 4;
        *(float4*)(&wt[tt * NW + sg * 4]) = *(const float4*)src;
    }
    __syncthreads();

    const int lane   = tid & 63;
    const int wv     = tid >> 6;
    const int h      = lane >> 3;
    const int base_b = lane * 224;           // 56 floats * 4B

#pragma unroll
    for (int qq = 0; qq < 4; ++qq) {
        const int tt = wv * 4 + qq;
        const int tb = tt * 2048 + base_b;
        float xv[56];
#pragma unroll
        for (int i = 0; i < 14; ++i)
            *(float4*)(&xv[i * 4]) = *(const float4*)((const char*)xs + swz(tb + i * 16));
        const float* wp = &wt[tt * NW + h * 7];
        float w[7];
#pragma unroll
        for (int k = 0; k < 7; ++k) w[k] = wp[k];
        float a[8];
#pragma unroll
        for (int r = 0; r < 8; ++r) {
            float s = xv[r * 7] * w[0];
#pragma unroll
            for (int k = 1; k < 7; ++k) s = fmaf(w[k], xv[r * 7 + k], s);
            a[r] = s;
        }
        float* orow = out + ((size_t)(t0 + tt) * B_DIM + b) * C_DIM + lane * 8;
        *(float4*)(orow)     = make_float4(a[0], a[1], a[2], a[3]);
        *(float4*)(orow + 4) = make_float4(a[4], a[5], a[6], a[7]);
    }
}

extern "C" void kernel_launch(void* const* d_in, const int* in_sizes, int n_in,
                              void* d_out, int out_size, void* d_ws, size_t ws_size,
                              hipStream_t stream) {
    const float* x = (const float*)d_in[0];
    const float* q = (const float*)d_in[1];
    const float* W = (const float*)d_in[2];
    float* out = (float*)d_out;
    float* wsw = (float*)d_ws;   // ROWS*NW floats = 7,340,032 bytes

    weights_kernel<<<ROWS / 64, 256, 0, stream>>>(q, W, wsw);
    conv_kernel<<<(T_DIM / 16) * B_DIM, 256, 0, stream>>>(x, wsw, out);
}

// Round 3
// 174.534 us; speedup vs baseline: 1.5128x; 1.1571x over previous
//
#include <hip/hip_runtime.h>

#define T_DIM 2048
#define B_DIM 16
#define C_DIM 512
#define NW 56            // H*K
#define XS_BYTES (22 * 512 * 2)       // bf16 x window, swizzled: 22528 B
#define A_OFF    XS_BYTES             // A-frag region (16 ks * 64 lanes * 16 B = 16384 B)
#define WT_OFF   (XS_BYTES + 4160)    // wt (fp32 16x56) lives after L (16x65x4 = 4160 B)
#define LDS_TOTAL (XS_BYTES + 16384)  // 38912 B -> 3-4 blocks/CU

typedef __attribute__((ext_vector_type(8))) short short8;
typedef __attribute__((ext_vector_type(4))) float floatx4;

static __device__ __forceinline__ unsigned short f2bf(float x) {
    union { float f; unsigned u; } v; v.f = x;
    return (unsigned short)((v.u + 0x7FFFu + ((v.u >> 16) & 1u)) >> 16);  // RNE
}
static __device__ __forceinline__ float bf_lo(unsigned u) {
    union { unsigned u; float f; } c; c.u = u << 16; return c.f;
}
static __device__ __forceinline__ float bf_hi(unsigned u) {
    union { unsigned u; float f; } c; c.u = u & 0xFFFF0000u; return c.f;
}
// 16B-block XOR swizzle for the bf16 xs layout: bank-group bits [6:4] ^= addr[9:7].
// Conv read pattern (lane stride 112 B) lands all 64 lanes on distinct groups.
static __device__ __forceinline__ int swz(int a) { return a ^ ((a >> 3) & 0x70); }

// ---------------------------------------------------------------------------
// Pre-kernel: pack W (512x56 fp32) into bf16 MFMA B-fragments, lane order:
// Bg[(ks*4+nt)*64 + l][j] = W[k = ks*32+(l>>4)*8+j][n = nt*16+(l&15)], 0-pad n>=56.
// 64 KB total -> L2-resident, broadcast to all fused blocks.
// ---------------------------------------------------------------------------
__global__ __launch_bounds__(256)
void pack_w(const float* __restrict__ W, short8* __restrict__ Bg) {
    const int g  = blockIdx.x * 256 + threadIdx.x;   // 0..4095
    const int ks = g >> 8;
    const int nt = (g >> 6) & 3;
    const int l  = g & 63;
    const int n  = nt * 16 + (l & 15);
    const int k0 = ks * 32 + ((l >> 4) & 3) * 8;
    short8 o;
#pragma unroll
    for (int j = 0; j < 8; ++j) {
        const float v = (n < NW) ? W[(size_t)(k0 + j) * NW + n] : 0.f;
        o[j] = (short)f2bf(v);
    }
    Bg[g] = o;
}

// ---------------------------------------------------------------------------
// Fused kernel: block = 16 t x 1 b.
//  1. issue q loads (A tile), all 16 B-frag loads, x-window loads
//  2. stage A in fragment order (conflict-free b128), sync
//  3. 16 MFMAs/wave (wave wv = ntile wv), B frags straight from registers
//  4. convert x -> bf16 xs (swizzled), sync; logits -> L (reuses A region), sync
//  5. softmax (128 tasks) -> wt in LDS, sync
//  6. conv: lane owns outputs 8l..8l+8 = window bytes [112l,112l+112) ->
//     7 uint4 LDS reads, unpack, 56 FMA, 2 float4 stores.
// ---------------------------------------------------------------------------
__global__ __launch_bounds__(256)
void fused_kernel(const float* __restrict__ x, const float* __restrict__ q,
                  const short8* __restrict__ Bg, float* __restrict__ out) {
    __shared__ __align__(16) char S[LDS_TOTAL];

    const int tid  = threadIdx.x;
    const int lane = tid & 63;
    const int wv   = tid >> 6;                 // wave id = ntile
    const int b    = blockIdx.x & 15;
    const int t0   = (blockIdx.x >> 4) * 16;

    // ---- issue q loads: thread (lane,wv) stages frags for lane, ks in {wv,wv+4,wv+8,wv+12}
    const int rq = lane & 15;                  // A row (= tt)
    const int qq = lane >> 4;                  // quad
    const float* qrow = q + ((size_t)(t0 + rq) * B_DIM + b) * C_DIM + qq * 8;
    float4 qr[4][2];
#pragma unroll
    for (int s = 0; s < 4; ++s) {
        const int ks = wv + s * 4;
        qr[s][0] = *(const float4*)(qrow + ks * 32);
        qr[s][1] = *(const float4*)(qrow + ks * 32 + 4);
    }
    // ---- issue all 16 B-frag loads (coalesced 16 B/lane, L2-hot)
    short8 bfr[16];
#pragma unroll
    for (int ks = 0; ks < 16; ++ks)
        bfr[ks] = Bg[(ks * 4 + wv) * 64 + lane];
    // ---- issue x-window loads (22 padded rows x 512 fp32)
    float4 xr[11];
#pragma unroll
    for (int j = 0; j < 11; ++j) {
        const int idx = tid + j * 256;         // float4 index 0..2815
        const int i   = idx >> 7;              // padded row 0..21
        const int c   = (idx & 127) * 4;
        const int tp  = t0 + i - 3;
        xr[j] = make_float4(0.f, 0.f, 0.f, 0.f);
        if (tp >= 0 && tp < T_DIM)
            xr[j] = *(const float4*)(x + ((size_t)tp * B_DIM + b) * C_DIM + c);
    }

    // ---- stage A tile in fragment order: A8[ks*64 + lane] = 8 bf16 (k-contig)
    short8* A8 = (short8*)(S + A_OFF);
#pragma unroll
    for (int s = 0; s < 4; ++s) {
        const int ks = wv + s * 4;
        short8 o;
        o[0] = (short)f2bf(qr[s][0].x); o[1] = (short)f2bf(qr[s][0].y);
        o[2] = (short)f2bf(qr[s][0].z); o[3] = (short)f2bf(qr[s][0].w);
        o[4] = (short)f2bf(qr[s][1].x); o[5] = (short)f2bf(qr[s][1].y);
        o[6] = (short)f2bf(qr[s][1].z); o[7] = (short)f2bf(qr[s][1].w);
        A8[ks * 64 + lane] = o;
    }
    __syncthreads();

    // ---- GEMM: logits tile 16 rows x 64 n; wave wv owns n-tile wv
    floatx4 acc = (floatx4){0.f, 0.f, 0.f, 0.f};
#pragma unroll
    for (int ks = 0; ks < 16; ++ks) {
        const short8 af = A8[ks * 64 + lane];
        acc = __builtin_amdgcn_mfma_f32_16x16x32_bf16(af, bfr[ks], acc, 0, 0, 0);
    }

    // ---- convert x -> bf16 xs (swizzled); xs region untouched by GEMM
    char* XS = S;
#pragma unroll
    for (int j = 0; j < 11; ++j) {
        const int idx = tid + j * 256;
        uint2 p;
        p.x = (unsigned)f2bf(xr[j].x) | ((unsigned)f2bf(xr[j].y) << 16);
        p.y = (unsigned)f2bf(xr[j].z) | ((unsigned)f2bf(xr[j].w) << 16);
        const int a = idx * 8;
        *(uint2*)(XS + swz(a)) = p;
    }
    __syncthreads();   // A reads done (GEMM finished in all waves) + xs visible

    // ---- logits -> L (reuses A region); D layout: row=quad*4+r, col=lane&15
    float* L = (float*)(S + A_OFF);
    const int m = lane & 15;
    const int quad = lane >> 4;
#pragma unroll
    for (int r = 0; r < 4; ++r)
        L[(quad * 4 + r) * 65 + wv * 16 + m] = acc[r];
    __syncthreads();

    // ---- softmax over groups of 7: 16 rows x 8 heads = 128 tasks -> wt (fp32)
    float* wt = (float*)(S + WT_OFF);
    if (tid < 128) {
        const int row = tid >> 3, h = tid & 7;
        const float* Lp = L + row * 65 + h * 7;
        float mx = Lp[0];
#pragma unroll
        for (int k = 1; k < 7; ++k) mx = fmaxf(mx, Lp[k]);
        float e[7], sm = 0.f;
#pragma unroll
        for (int k = 0; k < 7; ++k) { e[k] = __expf(Lp[k] - mx); sm += e[k]; }
        const float inv = 1.0f / sm;
#pragma unroll
        for (int k = 0; k < 7; ++k) wt[row * NW + h * 7 + k] = e[k] * inv;
    }
    __syncthreads();

    // ---- conv
    const int h = lane >> 3;
    const int base_b = lane * 112;             // 56 bf16 * 2 B
#pragma unroll
    for (int s = 0; s < 4; ++s) {
        const int tt = wv * 4 + s;
        const int tb = tt * 1024 + base_b;
        uint4 xu[7];
#pragma unroll
        for (int i = 0; i < 7; ++i)
            xu[i] = *(const uint4*)(XS + swz(tb + i * 16));
        float xf[56];
#pragma unroll
        for (int i = 0; i < 7; ++i) {
            xf[i * 8 + 0] = bf_lo(xu[i].x); xf[i * 8 + 1] = bf_hi(xu[i].x);
            xf[i * 8 + 2] = bf_lo(xu[i].y); xf[i * 8 + 3] = bf_hi(xu[i].y);
            xf[i * 8 + 4] = bf_lo(xu[i].z); xf[i * 8 + 5] = bf_hi(xu[i].z);
            xf[i * 8 + 6] = bf_lo(xu[i].w); xf[i * 8 + 7] = bf_hi(xu[i].w);
        }
        const float* wp = wt + tt * NW + h * 7;
        float w[7];
#pragma unroll
        for (int k = 0; k < 7; ++k) w[k] = wp[k];
        float a8[8];
#pragma unroll
        for (int r = 0; r < 8; ++r) {
            float sacc = xf[r * 7] * w[0];
#pragma unroll
            for (int k = 1; k < 7; ++k) sacc = fmaf(w[k], xf[r * 7 + k], sacc);
            a8[r] = sacc;
        }
        float* orow = out + ((size_t)(t0 + tt) * B_DIM + b) * C_DIM + lane * 8;
        *(float4*)(orow)     = make_float4(a8[0], a8[1], a8[2], a8[3]);
        *(float4*)(orow + 4) = make_float4(a8[4], a8[5], a8[6], a8[7]);
    }
}

extern "C" void kernel_launch(void* const* d_in, const int* in_sizes, int n_in,
                              void* d_out, int out_size, void* d_ws, size_t ws_size,
                              hipStream_t stream) {
    const float* x = (const float*)d_in[0];
    const float* q = (const float*)d_in[1];
    const float* W = (const float*)d_in[2];
    float* out = (float*)d_out;
    short8* Bg = (short8*)d_ws;   // 64 KB packed bf16 B-fragments

    pack_w<<<16, 256, 0, stream>>>(W, Bg);
    fused_kernel<<<(T_DIM / 16) * B_DIM, 256, 0, stream>>>(x, q, Bg, out);
}